// Round 7
// baseline (639.585 us; speedup 1.0000x reference)
//
#include <hip/hip_runtime.h>
#include <hip/hip_bf16.h>

#define B_    8
#define V_    100000
#define FIN_  32
#define K_    4
#define FOUT_ 64
#define E_    800000
#define NODE_F 256   // B_ * FIN_ elements per node row

typedef __attribute__((ext_vector_type(8))) short bf16x8;
typedef __attribute__((ext_vector_type(4))) float floatx4;

static __device__ inline float bf2f(unsigned short u) {
    unsigned int x = ((unsigned int)u) << 16;
    return __builtin_bit_cast(float, x);
}
static __device__ inline unsigned short f2bf(float f) {
    __hip_bfloat16 h = __float2bfloat16(f);   // RNE
    return __builtin_bit_cast(unsigned short, h);
}

static __device__ inline float wave_max64(float m) {
    #pragma unroll
    for (int off = 1; off < 64; off <<= 1)
        m = fmaxf(m, __shfl_xor(m, off));
    return m;
}

// Quantize one node row (wave-wide, lane owns features [4*lane, 4*lane+4))
// to int8-biased-128 with per-row dequant scale d = max/127  (x ~= (u-128)*d).
static __device__ inline void quant_store(const float r[4], int v, int lane,
                                          unsigned char* __restrict__ xi,
                                          float* __restrict__ sc) {
    float m = fmaxf(fmaxf(fabsf(r[0]), fabsf(r[1])), fmaxf(fabsf(r[2]), fabsf(r[3])));
    m = wave_max64(m);
    float inv = (m > 0.f) ? 127.f / m : 0.f;
    if (lane == 0) sc[v] = (m > 0.f) ? m * (1.f / 127.f) : 0.f;
    unsigned int q = 0;
    #pragma unroll
    for (int j = 0; j < 4; ++j) {
        int qi = (int)rintf(r[j] * inv) + 128;   // in [1,255]
        q |= ((unsigned int)(qi & 0xff)) << (8 * j);
    }
    ((unsigned int*)(xi + (size_t)v * NODE_F))[lane] = q;
}

// ---------------- fused prologue: transpose + x0 quant + hist + weight pack -
__global__ __launch_bounds__(256) void k_transpose(const float* __restrict__ in,
                                                   unsigned short* __restrict__ x0,
                                                   unsigned char* __restrict__ x0i,
                                                   float* __restrict__ s0,
                                                   const int* __restrict__ rows,
                                                   int* __restrict__ counts,
                                                   const float* __restrict__ weight,
                                                   unsigned short* __restrict__ wpack) {
    int tid = blockIdx.x * 256 + threadIdx.x;     // over V_*B_*8 groups of 4
    int lane = threadIdx.x & 63;                  // wave == one node row
    int f4 = tid & 7;
    int m  = tid >> 3;          // m = v*8 + b
    int v  = m >> 3;
    int b  = m & 7;
    float4 val = ((const float4*)(in + ((size_t)b * V_ + v) * FIN_))[f4];
    ushort4 o;
    o.x = f2bf(val.x); o.y = f2bf(val.y); o.z = f2bf(val.z); o.w = f2bf(val.w);
    ((ushort4*)x0)[tid] = o;

    // int8 copy for the gather path (lane*4 == b*32 + f4*4, full row per wave)
    float r[4] = {val.x, val.y, val.z, val.w};
    quant_store(r, v, lane, x0i, s0);

    if (tid < E_) atomicAdd(&counts[rows[tid]], 1);

    if (tid < 1024) {   // wpack[kq][ot][lane][j] = bf16(W[f=quad*8+j][kq][o=ot*16+l16])
        int l = tid & 63;
        int ot   = (tid >> 6) & 3;
        int kq   = tid >> 8;
        int quad = l >> 4, l16 = l & 15;
        bf16x8 w;
        #pragma unroll
        for (int j = 0; j < 8; ++j)
            w[j] = (short)f2bf(weight[(size_t)(quad * 8 + j) * (K_ * FOUT_) + kq * FOUT_ + ot * 16 + l16]);
        *((bf16x8*)(wpack + (size_t)tid * 8)) = w;
    }
}

// ---------------- CSR build ------------------------------------------------
__global__ __launch_bounds__(256) void k_zero_int(int* __restrict__ p, int n) {
    int t = blockIdx.x * 256 + threadIdx.x;
    if (t < n) p[t] = 0;
}

__global__ __launch_bounds__(1024) void k_scan1(const int* __restrict__ counts,
                                                int* __restrict__ row_ptr,
                                                int* __restrict__ cursor,
                                                int* __restrict__ bsums, int n) {
    __shared__ int s[1024];
    int t = threadIdx.x;
    int idx = blockIdx.x * 1024 + t;
    int v = (idx < n) ? counts[idx] : 0;
    s[t] = v;
    __syncthreads();
    for (int off = 1; off < 1024; off <<= 1) {
        int add = (t >= off) ? s[t - off] : 0;
        __syncthreads();
        s[t] += add;
        __syncthreads();
    }
    if (idx < n) {
        int r = s[t] - v;   // exclusive, block-local
        row_ptr[idx] = r;
        cursor[idx]  = r;
    }
    if (t == 1023) bsums[blockIdx.x] = s[1023];
}

__global__ __launch_bounds__(128) void k_scan2(const int* __restrict__ bsums,
                                               int* __restrict__ boffs, int nb) {
    __shared__ int s[128];
    int t = threadIdx.x;
    int v = (t < nb) ? bsums[t] : 0;
    s[t] = v;
    __syncthreads();
    for (int off = 1; off < 128; off <<= 1) {
        int add = (t >= off) ? s[t - off] : 0;
        __syncthreads();
        s[t] += add;
        __syncthreads();
    }
    boffs[t] = s[t] - v;
}

__global__ __launch_bounds__(256) void k_scatter(const int* __restrict__ rows,
                                                 const int* __restrict__ cols,
                                                 const float* __restrict__ vals,
                                                 int* __restrict__ cursor,
                                                 const int* __restrict__ boffs,
                                                 int2* __restrict__ e_pack) {
    int e = blockIdx.x * 256 + threadIdx.x;
    if (e < E_) {
        int r = rows[e];
        int pos = atomicAdd(&cursor[r], 1) + boffs[r >> 10];
        e_pack[pos] = make_int2(cols[e], __float_as_int(vals[e]));
    }
}

// ---------------- SpMM body: int8 gathers, full-wave per edge --------------
// One edge per wave-iteration: 64 lanes x 4 B = 256 B row gather.
// w_e = val_e * d[col];  S_j = sum_e w_e*(u_j - 128) = (sum w*u_j) - 128*sum(w).
static __device__ inline void spmm_row_i8(const unsigned char* __restrict__ xi,
                                          const float* __restrict__ sc,
                                          const int2* __restrict__ ep,
                                          int beg, int end, int lane,
                                          float a[4], float* swp) {
    float sw = 0.f;
    int e = beg;
    for (; e + 3 < end; e += 4) {
        int2 p0 = ep[e], p1 = ep[e + 1], p2 = ep[e + 2], p3 = ep[e + 3];
        unsigned int g0 = ((const unsigned int*)(xi + (size_t)p0.x * NODE_F))[lane];
        unsigned int g1 = ((const unsigned int*)(xi + (size_t)p1.x * NODE_F))[lane];
        unsigned int g2 = ((const unsigned int*)(xi + (size_t)p2.x * NODE_F))[lane];
        unsigned int g3 = ((const unsigned int*)(xi + (size_t)p3.x * NODE_F))[lane];
        float w0 = __int_as_float(p0.y) * sc[p0.x];
        float w1 = __int_as_float(p1.y) * sc[p1.x];
        float w2 = __int_as_float(p2.y) * sc[p2.x];
        float w3 = __int_as_float(p3.y) * sc[p3.x];
        sw += w0 + w1 + w2 + w3;
        a[0] += w0 * (float)(g0 & 0xff);         a[1] += w0 * (float)((g0 >> 8) & 0xff);
        a[2] += w0 * (float)((g0 >> 16) & 0xff); a[3] += w0 * (float)(g0 >> 24);
        a[0] += w1 * (float)(g1 & 0xff);         a[1] += w1 * (float)((g1 >> 8) & 0xff);
        a[2] += w1 * (float)((g1 >> 16) & 0xff); a[3] += w1 * (float)(g1 >> 24);
        a[0] += w2 * (float)(g2 & 0xff);         a[1] += w2 * (float)((g2 >> 8) & 0xff);
        a[2] += w2 * (float)((g2 >> 16) & 0xff); a[3] += w2 * (float)(g2 >> 24);
        a[0] += w3 * (float)(g3 & 0xff);         a[1] += w3 * (float)((g3 >> 8) & 0xff);
        a[2] += w3 * (float)((g3 >> 16) & 0xff); a[3] += w3 * (float)(g3 >> 24);
    }
    for (; e < end; ++e) {
        int2 p = ep[e];
        unsigned int g = ((const unsigned int*)(xi + (size_t)p.x * NODE_F))[lane];
        float w = __int_as_float(p.y) * sc[p.x];
        sw += w;
        a[0] += w * (float)(g & 0xff);         a[1] += w * (float)((g >> 8) & 0xff);
        a[2] += w * (float)((g >> 16) & 0xff); a[3] += w * (float)(g >> 24);
    }
    *swp = sw;
}

// one Chebyshev SpMM pass, grid-stride over nodes
static __device__ inline void phase_pass(int gw, int nw, int lane,
                                         const unsigned char* __restrict__ xci,
                                         const float* __restrict__ sci,
                                         const unsigned short* __restrict__ xp,
                                         int has_prev, float scale,
                                         unsigned short* __restrict__ xn,   // nullable
                                         unsigned char* __restrict__ xni,
                                         float* __restrict__ scn,
                                         const int* __restrict__ row_ptr,
                                         const int* __restrict__ boffs,
                                         const int2* __restrict__ ep) {
    #pragma unroll 1
    for (int v = gw; v < V_; v += nw) {
        int beg = row_ptr[v] + boffs[v >> 10];
        int end = (v == V_ - 1) ? E_ : row_ptr[v + 1] + boffs[(v + 1) >> 10];
        float a[4] = {0.f, 0.f, 0.f, 0.f};
        float sw;
        spmm_row_i8(xci, sci, ep, beg, end, lane, a, &sw);
        float r[4];
        #pragma unroll
        for (int j = 0; j < 4; ++j) r[j] = a[j] - 128.f * sw;
        if (has_prev) {
            ushort4 p = *((const ushort4*)(xp + (size_t)v * NODE_F + lane * 4));
            r[0] = scale * r[0] - bf2f(p.x);
            r[1] = scale * r[1] - bf2f(p.y);
            r[2] = scale * r[2] - bf2f(p.z);
            r[3] = scale * r[3] - bf2f(p.w);
        }
        if (xn) {
            ushort4 o;
            o.x = f2bf(r[0]); o.y = f2bf(r[1]); o.z = f2bf(r[2]); o.w = f2bf(r[3]);
            *((ushort4*)(xn + (size_t)v * NODE_F + lane * 4)) = o;
        }
        quant_store(r, v, lane, xni, scn);
    }
}

static __device__ inline void mfma4(const unsigned short* __restrict__ wpack,
                                    int kq, int lane, bf16x8 xf, floatx4 acc[4]) {
    #pragma unroll
    for (int ot = 0; ot < 4; ++ot) {
        bf16x8 wf = *((const bf16x8*)(wpack + (size_t)((kq * 4 + ot) * 64 + lane) * 8));
        acc[ot] = __builtin_amdgcn_mfma_f32_16x16x32_bf16(wf, xf, acc[ot], 0, 0, 0);
    }
}

// pass-3 SpMM (x3 = 2*L*x2 - x1, per node pair -> LDS) + MFMA contraction.
// contract operands: kq0 = x0 bf16, kq1 = x1 bf16 (same lines as xp read),
// kq2 = x2i dequant (int8 + per-row scale), kq3 = x3 from LDS.
static __device__ inline void phase_contract(int gw, int nw, int lane,
                                             unsigned short* __restrict__ x3sw,  // LDS [2][NODE_F]
                                             const unsigned short* __restrict__ x0,
                                             const unsigned short* __restrict__ x1,
                                             const unsigned char* __restrict__ x2i,
                                             const float* __restrict__ s2,
                                             const int* __restrict__ row_ptr,
                                             const int* __restrict__ boffs,
                                             const int2* __restrict__ ep,
                                             const unsigned short* __restrict__ wpack,
                                             const float* __restrict__ bias,
                                             float* __restrict__ out) {
    int quad = lane >> 4;
    int l16  = lane & 15;
    floatx4 bi[4];
    #pragma unroll
    for (int ot = 0; ot < 4; ++ot)
        bi[ot] = *((const floatx4*)(bias + ot * 16 + quad * 4));

    #pragma unroll 1
    for (int pair = gw; pair < V_ / 2; pair += nw) {
        // x3 rows for the two nodes of this pair (per-wave LDS, no barrier)
        #pragma unroll 1
        for (int s = 0; s < 2; ++s) {
            int v = pair * 2 + s;
            int beg = row_ptr[v] + boffs[v >> 10];
            int end = (v == V_ - 1) ? E_ : row_ptr[v + 1] + boffs[(v + 1) >> 10];
            float a[4] = {0.f, 0.f, 0.f, 0.f};
            float sw;
            spmm_row_i8(x2i, s2, ep, beg, end, lane, a, &sw);
            ushort4 p1 = *((const ushort4*)(x1 + (size_t)v * NODE_F + lane * 4));
            ushort4 o;
            o.x = f2bf(2.f * (a[0] - 128.f * sw) - bf2f(p1.x));
            o.y = f2bf(2.f * (a[1] - 128.f * sw) - bf2f(p1.y));
            o.z = f2bf(2.f * (a[2] - 128.f * sw) - bf2f(p1.z));
            o.w = f2bf(2.f * (a[3] - 128.f * sw) - bf2f(p1.w));
            *((ushort4*)(x3sw + s * NODE_F + lane * 4)) = o;
        }

        int m0 = pair * 16;
        int vA = pair * 2 + (l16 >> 3);   // node of this lane's m-row
        int bA = l16 & 7;
        floatx4 acc[4] = {bi[0], bi[1], bi[2], bi[3]};   // bias pre-seeded

        {   // kq = 0: x0 bf16 stream
            bf16x8 xf = *((const bf16x8*)(x0 + (size_t)(m0 + l16) * FIN_ + quad * 8));
            mfma4(wpack, 0, lane, xf, acc);
        }
        {   // kq = 1: x1 bf16 (rides the xp lines)
            bf16x8 xf = *((const bf16x8*)(x1 + (size_t)(m0 + l16) * FIN_ + quad * 8));
            mfma4(wpack, 1, lane, xf, acc);
        }
        {   // kq = 2: dequant x2i
            float s = s2[vA];
            const unsigned int* p = (const unsigned int*)(x2i + (size_t)vA * NODE_F + bA * FIN_ + quad * 8);
            unsigned int d0 = p[0], d1 = p[1];
            bf16x8 xf;
            #pragma unroll
            for (int j = 0; j < 4; ++j)
                xf[j] = (short)f2bf(((float)((d0 >> (8 * j)) & 0xff) - 128.f) * s);
            #pragma unroll
            for (int j = 0; j < 4; ++j)
                xf[4 + j] = (short)f2bf(((float)((d1 >> (8 * j)) & 0xff) - 128.f) * s);
            mfma4(wpack, 2, lane, xf, acc);
        }
        {   // kq = 3: x3 from LDS
            bf16x8 xf = *((const bf16x8*)(x3sw + (l16 >> 3) * NODE_F + (l16 & 7) * FIN_ + quad * 8));
            mfma4(wpack, 3, lane, xf, acc);
        }

        // D: col = lane&15 = m-row, row = quad*4+r = o  =>  float4 stores
        int m = m0 + l16;
        int v = m >> 3;
        int b = m & 7;
        float* op = out + ((size_t)b * V_ + v) * FOUT_ + quad * 4;
        #pragma unroll
        for (int ot = 0; ot < 4; ++ot)
            *((floatx4*)(op + ot * 16)) = acc[ot];
    }
}

// ---------------- phase kernels (plain launches, grid-stride) --------------
__global__ __launch_bounds__(256) void k_p1(const unsigned char* __restrict__ x0i,
                                            const float* __restrict__ s0,
                                            unsigned short* __restrict__ x1,
                                            unsigned char* __restrict__ x1i,
                                            float* __restrict__ s1,
                                            const int* __restrict__ row_ptr,
                                            const int* __restrict__ boffs,
                                            const int2* __restrict__ ep) {
    int gw = blockIdx.x * 4 + (threadIdx.x >> 6);
    phase_pass(gw, gridDim.x * 4, threadIdx.x & 63, x0i, s0,
               (const unsigned short*)nullptr, 0, 1.f, x1, x1i, s1, row_ptr, boffs, ep);
}

__global__ __launch_bounds__(256) void k_p2(const unsigned char* __restrict__ x1i,
                                            const float* __restrict__ s1,
                                            const unsigned short* __restrict__ x0,
                                            unsigned char* __restrict__ x2i,
                                            float* __restrict__ s2,
                                            const int* __restrict__ row_ptr,
                                            const int* __restrict__ boffs,
                                            const int2* __restrict__ ep) {
    int gw = blockIdx.x * 4 + (threadIdx.x >> 6);
    phase_pass(gw, gridDim.x * 4, threadIdx.x & 63, x1i, s1, x0, 1, 2.f,
               (unsigned short*)nullptr, x2i, s2, row_ptr, boffs, ep);
}

__global__ __launch_bounds__(256) void k_p3(const unsigned short* __restrict__ x0,
                                            const unsigned short* __restrict__ x1,
                                            const unsigned char* __restrict__ x2i,
                                            const float* __restrict__ s2,
                                            const int* __restrict__ row_ptr,
                                            const int* __restrict__ boffs,
                                            const int2* __restrict__ ep,
                                            const unsigned short* __restrict__ wpack,
                                            const float* __restrict__ bias,
                                            float* __restrict__ out) {
    __shared__ __align__(16) unsigned short x3s[4][2][NODE_F];
    int wave = threadIdx.x >> 6;
    int gw = blockIdx.x * 4 + wave;
    phase_contract(gw, gridDim.x * 4, threadIdx.x & 63, &x3s[wave][0][0],
                   x0, x1, x2i, s2, row_ptr, boffs, ep, wpack, bias, out);
}

// ---------------- launcher -------------------------------------------------
extern "C" void kernel_launch(void* const* d_in, const int* in_sizes, int n_in,
                              void* d_out, int out_size, void* d_ws, size_t ws_size,
                              hipStream_t stream) {
    const float* inputs  = (const float*)d_in[0];
    const int*   laprows = (const int*)d_in[1];
    const int*   lapcols = (const int*)d_in[2];
    const float* lapvals = (const float*)d_in[3];
    const float* weight  = (const float*)d_in[4];
    const float* bias    = (const float*)d_in[5];
    float* out = (float*)d_out;

    const size_t XN  = (size_t)V_ * NODE_F;   // elements per buffer
    unsigned short* x0 = (unsigned short*)d_ws;               // bf16
    unsigned short* x1 = x0 + XN;                             // bf16
    unsigned char* x0i = (unsigned char*)(x1 + XN);           // int8
    unsigned char* x1i = x0i + XN;
    unsigned char* x2i = x1i + XN;
    float* s0 = (float*)(x2i + XN);
    float* s1 = s0 + V_;
    float* s2 = s1 + V_;
    int* counts  = (int*)(s2 + V_);
    int* row_ptr = counts + V_;
    int* cursor  = row_ptr + V_;
    int* bsums   = cursor + V_;
    int* boffs   = bsums + 128;
    unsigned short* wpack = (unsigned short*)(boffs + 128);   // 16 KB, 16B-aligned
    int2* e_pack = (int2*)(wpack + 8192);                     // 8B-aligned

    const int NB_SCAN = (V_ + 1023) / 1024;   // 98

    hipLaunchKernelGGL(k_zero_int, dim3((V_ + 255) / 256), dim3(256), 0, stream, counts, V_);
    hipLaunchKernelGGL(k_transpose, dim3((V_ * B_ * 8) / 256), dim3(256), 0, stream,
                       inputs, x0, x0i, s0, laprows, counts, weight, wpack);
    hipLaunchKernelGGL(k_scan1, dim3(NB_SCAN), dim3(1024), 0, stream,
                       counts, row_ptr, cursor, bsums, V_);
    hipLaunchKernelGGL(k_scan2, dim3(1), dim3(128), 0, stream, bsums, boffs, NB_SCAN);
    hipLaunchKernelGGL(k_scatter, dim3((E_ + 255) / 256), dim3(256), 0, stream,
                       laprows, lapcols, lapvals, cursor, boffs, e_pack);

    // x1 = L x0 ; x2 = 2 L x1 - x0 (int8-only) ; x3 fused into contraction
    hipLaunchKernelGGL(k_p1, dim3(6250), dim3(256), 0, stream,
                       x0i, s0, x1, x1i, s1, row_ptr, boffs, e_pack);
    hipLaunchKernelGGL(k_p2, dim3(6250), dim3(256), 0, stream,
                       x1i, s1, x0, x2i, s2, row_ptr, boffs, e_pack);
    hipLaunchKernelGGL(k_p3, dim3(3125), dim3(256), 0, stream,
                       x0, x1, x2i, s2, row_ptr, boffs, e_pack, wpack, bias, out);
}